// Round 12
// baseline (245.962 us; speedup 1.0000x reference)
//
#include <hip/hip_runtime.h>
#include <hip/hip_bf16.h>
#include <math.h>

#define Lseq 2048
#define Dmod 1024
#define DI   2048
#define Nst  16
#define DRr  64
#define NCHUNK 32
#define LCHUNK 64
#define SPLITK 16
#define OSPLIT 4

typedef unsigned short u16;
typedef float  f32x4  __attribute__((ext_vector_type(4)));
typedef short  short8 __attribute__((ext_vector_type(8)));

__device__ __forceinline__ float sigmoidf_(float x) { return 1.f / (1.f + expf(-x)); }
__device__ __forceinline__ float softplusf_(float x) {
    return fmaxf(x, 0.f) + log1pf(expf(-fabsf(x)));
}
__device__ __forceinline__ u16 f2bf(float x) {
    union { float f; unsigned u; } v; v.f = x;
    unsigned r = (v.u + 0x7fffu + ((v.u >> 16) & 1u)) >> 16;
    return (u16)r;
}
__device__ __forceinline__ float bf2f(u16 h) {
    union { unsigned u; float f; } v; v.u = ((unsigned)h) << 16; return v.f;
}
__device__ __forceinline__ void async16(const void* g, void* l) {
    __builtin_amdgcn_global_load_lds((__attribute__((address_space(1))) void*)g,
                                     (__attribute__((address_space(3))) void*)l, 16, 0, 0);
}

struct __align__(8) u16x4 { u16 x, y, z, w; };

// ---------------- Weight transpose + split body ----------------
__device__ __forceinline__ void wsplit_body(const float* __restrict__ W, int R, int Cn,
                                            int bx, int by, float (*t)[33],
                                            u16* __restrict__ Th, u16* __restrict__ Tl) {
    int r0 = by * 32, c0 = bx * 32;
    int tr = threadIdx.x >> 3;
    int tc4 = (threadIdx.x & 7) * 4;
    float4 v = *reinterpret_cast<const float4*>(&W[(size_t)(r0 + tr) * Cn + c0 + tc4]);
    t[tr][tc4 + 0] = v.x; t[tr][tc4 + 1] = v.y;
    t[tr][tc4 + 2] = v.z; t[tr][tc4 + 3] = v.w;
    __syncthreads();
    u16x4 H, L;
    u16* hp = &H.x; u16* lp = &L.x;
    #pragma unroll
    for (int q = 0; q < 4; q++) {
        float xv = t[tc4 + q][tr];
        u16 h = f2bf(xv); hp[q] = h; lp[q] = f2bf(xv - bf2f(h));
    }
    size_t o = (size_t)(c0 + tr) * R + r0 + tc4;
    *reinterpret_cast<u16x4*>(&Th[o]) = H;
    *reinterpret_cast<u16x4*>(&Tl[o]) = L;
}

// ---------------- prep1: rmsnorm + Wi + bcd_w + dup_w (+Wo if extended ws) ---------
__global__ __launch_bounds__(256) void prep1_k(const float* __restrict__ x,
                                               const float* __restrict__ rms_w,
                                               u16* __restrict__ xnH, u16* __restrict__ xnL,
                                               const float* __restrict__ Wi,
                                               u16* __restrict__ WiH, u16* __restrict__ WiL,
                                               const float* __restrict__ Wb,
                                               u16* __restrict__ bwTH, u16* __restrict__ bwTL,
                                               const float* __restrict__ Wd,
                                               u16* __restrict__ dwTH, u16* __restrict__ dwTL,
                                               const float* __restrict__ Wo,
                                               u16* __restrict__ WoH, u16* __restrict__ WoL) {
    __shared__ float t[32][33];
    __shared__ float s4[4];
    int b = blockIdx.x;
    if (b < 2048) {
        int row = b, tid = threadIdx.x;
        float4 v = reinterpret_cast<const float4*>(x + (size_t)row * Dmod)[tid];
        float ss = v.x * v.x + v.y * v.y + v.z * v.z + v.w * v.w;
        #pragma unroll
        for (int m = 32; m >= 1; m >>= 1) ss += __shfl_xor(ss, m);
        if ((tid & 63) == 0) s4[tid >> 6] = ss;
        __syncthreads();
        float tot = s4[0] + s4[1] + s4[2] + s4[3];
        float scale = rsqrtf(tot * (1.0f / Dmod) + 1e-5f);
        float4 wv = reinterpret_cast<const float4*>(rms_w)[tid];
        float o[4] = {v.x * scale * wv.x, v.y * scale * wv.y,
                      v.z * scale * wv.z, v.w * scale * wv.w};
        u16x4 H, L;
        u16* hp = &H.x; u16* lp = &L.x;
        #pragma unroll
        for (int q = 0; q < 4; q++) {
            u16 h = f2bf(o[q]); hp[q] = h; lp[q] = f2bf(o[q] - bf2f(h));
        }
        reinterpret_cast<u16x4*>(xnH + (size_t)row * Dmod)[tid] = H;
        reinterpret_cast<u16x4*>(xnL + (size_t)row * Dmod)[tid] = L;
    } else if (b < 2048 + 4096) {
        int bb = b - 2048;                 // in_proj_w (1024 x 4096): grid (128 x 32)
        wsplit_body(Wi, 1024, 4096, bb & 127, bb >> 7, t, WiH, WiL);
    } else if (b < 2048 + 4096 + 192) {
        int bb = b - (2048 + 4096);        // bcd_w (2048 x 96): grid (3 x 64)
        wsplit_body(Wb, 2048, 96, bb % 3, bb / 3, t, bwTH, bwTL);
    } else if (b < 2048 + 4096 + 192 + 128) {
        int bb = b - (2048 + 4096 + 192);  // dup_w (64 x 2048): grid (64 x 2)
        wsplit_body(Wd, 64, 2048, bb & 63, bb >> 6, t, dwTH, dwTL);
    } else {
        int bb = b - (2048 + 4096 + 192 + 128);  // out_proj_w (2048 x 1024): grid (32 x 64)
        wsplit_body(Wo, 2048, 1024, bb & 31, bb >> 5, t, WoH, WoL);
    }
}

// Fallback Wo-prep (ws too small for extended layout; runs after in_proj)
__global__ __launch_bounds__(256) void wsplitT_k(const float* __restrict__ W, int R, int Cn,
                                                 u16* __restrict__ Th, u16* __restrict__ Tl) {
    __shared__ float t[32][33];
    wsplit_body(W, R, Cn, blockIdx.x, blockIdx.y, t, Th, Tl);
}

// ---------------- Split-bf16 MFMA GEMM (R9 single-barrier pipeline, swizzled) ------
// C[M][N] = A[M][K] @ Bt[N][K]^T.  nt<=2 fast path: preload both tiles, no mid waits.
// EPI: 2 C=softplus(acc+aux[col]); 4 dual in_proj (cols<DI -> U1/U2 split bf16,
//      cols>=DI -> C2=silu); 5 split-K partial write to C.
template <int BM, int BN, int EPI>
__global__ __launch_bounds__(256) void gemm_mfma3(
    const u16* __restrict__ Ah, const u16* __restrict__ Al,
    const u16* __restrict__ Bh, const u16* __restrict__ Bl,
    float* __restrict__ C, float* __restrict__ C2,
    u16* __restrict__ U1, u16* __restrict__ U2,
    const float* __restrict__ aux,
    int M, int N, int K) {
    constexpr int BK = 32;
    constexpr int MF = BM / 32, NF = BN / 32;
    constexpr int CH_A = BM / 16, CH_B = BN / 16;
    __shared__ u16 AhT[2][BM][BK], AlT[2][BM][BK], BhT[2][BN][BK], BlT[2][BN][BK];
    const int tid = threadIdx.x, lane = tid & 63, wid = tid >> 6;
    const int wr = wid >> 1, wc = wid & 1;
    const int lr = lane & 15;
    const int sw = (lane >> 1) & 3;
    const int lkq = ((lane >> 4) ^ sw) * 8;              // swizzled read col-block
    const int bm0 = blockIdx.y * BM, bn0 = blockIdx.x * BN;
    const int srow = lane >> 2;
    const int scol_ = ((lane & 3) ^ ((lane >> 3) & 3)) * 8;   // pre-swizzled source col

    int kbeg = 0, kend = K;
    if (EPI == 5) {
        int ks = K / gridDim.z;
        kbeg = blockIdx.z * ks;
        kend = kbeg + ks;
    }
    const int nt = (kend - kbeg) / BK;

    auto STAGE = [&](int buf, int k0) {
        int ci = 0;
        #pragma unroll
        for (int c = 0; c < CH_A; c++, ci++) if ((ci & 3) == wid) {
            size_t g = (size_t)(bm0 + c * 16 + srow) * K + (k0 + scol_);
            async16(Ah + g, (u16*)&AhT[buf][0][0] + c * 512 + lane * 8);
        }
        #pragma unroll
        for (int c = 0; c < CH_A; c++, ci++) if ((ci & 3) == wid) {
            size_t g = (size_t)(bm0 + c * 16 + srow) * K + (k0 + scol_);
            async16(Al + g, (u16*)&AlT[buf][0][0] + c * 512 + lane * 8);
        }
        #pragma unroll
        for (int c = 0; c < CH_B; c++, ci++) if ((ci & 3) == wid) {
            size_t g = (size_t)(bn0 + c * 16 + srow) * K + (k0 + scol_);
            async16(Bh + g, (u16*)&BhT[buf][0][0] + c * 512 + lane * 8);
        }
        #pragma unroll
        for (int c = 0; c < CH_B; c++, ci++) if ((ci & 3) == wid) {
            size_t g = (size_t)(bn0 + c * 16 + srow) * K + (k0 + scol_);
            async16(Bl + g, (u16*)&BlT[buf][0][0] + c * 512 + lane * 8);
        }
    };

    f32x4 acc[MF][NF];
    #pragma unroll
    for (int i = 0; i < MF; i++)
        #pragma unroll
        for (int j = 0; j < NF; j++) acc[i][j] = (f32x4){0.f, 0.f, 0.f, 0.f};

    auto COMPUTE = [&](int cur) {
        short8 ah[MF], al[MF], bh[NF], bl[NF];
        #pragma unroll
        for (int i = 0; i < MF; i++) {
            int r = wr * (MF * 16) + i * 16 + lr;
            ah[i] = *(const short8*)&AhT[cur][r][lkq];
            al[i] = *(const short8*)&AlT[cur][r][lkq];
        }
        #pragma unroll
        for (int j = 0; j < NF; j++) {
            int r = wc * (NF * 16) + j * 16 + lr;
            bh[j] = *(const short8*)&BhT[cur][r][lkq];
            bl[j] = *(const short8*)&BlT[cur][r][lkq];
        }
        asm volatile("s_waitcnt lgkmcnt(0)" ::: "memory");
        __builtin_amdgcn_sched_barrier(0);
        __builtin_amdgcn_s_setprio(1);
        #pragma unroll
        for (int i = 0; i < MF; i++)
            #pragma unroll
            for (int j = 0; j < NF; j++) {
                acc[i][j] = __builtin_amdgcn_mfma_f32_16x16x32_bf16(ah[i], bh[j], acc[i][j], 0, 0, 0);
                acc[i][j] = __builtin_amdgcn_mfma_f32_16x16x32_bf16(ah[i], bl[j], acc[i][j], 0, 0, 0);
                acc[i][j] = __builtin_amdgcn_mfma_f32_16x16x32_bf16(al[i], bh[j], acc[i][j], 0, 0, 0);
            }
        __builtin_amdgcn_s_setprio(0);
    };

    if (nt <= 2) {
        // fast path: both tiles staged once; no LDS rewrite -> no mid-loop sync at all
        STAGE(0, kbeg);
        if (nt > 1) STAGE(1, kbeg + BK);
        asm volatile("s_waitcnt vmcnt(0)" ::: "memory");
        __builtin_amdgcn_s_barrier();
        COMPUTE(0);
        if (nt > 1) COMPUTE(1);
    } else {
        STAGE(0, kbeg);
        asm volatile("s_waitcnt vmcnt(0)" ::: "memory");
        __builtin_amdgcn_s_barrier();
        for (int t = 0; t < nt; ++t) {
            const int cur = t & 1;
            if (t + 1 < nt) STAGE(cur ^ 1, kbeg + (t + 1) * BK);
            COMPUTE(cur);
            if (t + 1 < nt) {
                asm volatile("s_waitcnt vmcnt(0)" ::: "memory");
                __builtin_amdgcn_s_barrier();
            }
        }
    }

    float* Cp = C;
    if (EPI == 5) Cp = C + (size_t)blockIdx.z * M * N;
    #pragma unroll
    for (int i = 0; i < MF; i++)
        #pragma unroll
        for (int j = 0; j < NF; j++) {
            int rowg = bm0 + wr * (MF * 16) + i * 16 + (lane >> 4) * 4;
            int colg = bn0 + wc * (NF * 16) + j * 16 + lr;
            #pragma unroll
            for (int q = 0; q < 4; q++) {
                float v = acc[i][j][q];
                if (EPI == 5) {
                    Cp[(size_t)(rowg + q) * N + colg] = v;
                } else if (EPI == 2) {
                    C[(size_t)(rowg + q) * N + colg] = softplusf_(v + aux[colg]);
                } else if (EPI == 4) {
                    if (colg < DI) {
                        size_t o = (size_t)(rowg + q) * DI + colg;
                        u16 hh = f2bf(v);
                        U1[o] = hh;
                        U2[o] = f2bf(v - bf2f(hh));
                    } else {
                        C2[(size_t)(rowg + q) * DI + (colg - DI)] = v * sigmoidf_(v);
                    }
                }
            }
        }
}

// ---------------- bcd split-K reduce ----------------
__global__ __launch_bounds__(256) void bcd_reduce_k(const float* __restrict__ partial,
                                                    float* __restrict__ bcd,
                                                    u16* __restrict__ bH,
                                                    u16* __restrict__ bL) {
    const int NT = Lseq * 96;
    int t = blockIdx.x * 256 + threadIdx.x;
    float s = 0.f;
    #pragma unroll
    for (int z = 0; z < SPLITK; z++) s += partial[(size_t)z * NT + t];
    bcd[t] = s;
    int col = t % 96, row = t / 96;
    if (col < DRr) {
        u16 h = f2bf(s);
        bH[(size_t)row * DRr + col] = h;
        bL[(size_t)row * DRr + col] = f2bf(s - bf2f(h));
    }
}

// ---------------- out split-K=4 reduce + residual ----------------
__global__ __launch_bounds__(256) void out_reduce_k(const float* __restrict__ part,
                                                    const float* __restrict__ x,
                                                    float* __restrict__ out) {
    int t = blockIdx.x * 256 + threadIdx.x;
    const size_t NT = (size_t)Lseq * Dmod;
    float4 xv = reinterpret_cast<const float4*>(x)[t];
    float4 o = xv;
    #pragma unroll
    for (int z = 0; z < OSPLIT; z++) {
        float4 p = reinterpret_cast<const float4*>(part + (size_t)z * NT)[t];
        o.x += p.x; o.y += p.y; o.z += p.z; o.w += p.w;
    }
    reinterpret_cast<float4*>(out)[t] = o;
}

// ---------------- Conv1d(K=4)+SiLU, rolling window, split-bf16 in/out ----------
__global__ __launch_bounds__(256) void conv_silu_k(const u16* __restrict__ xsH,
                                                   const u16* __restrict__ xsL,
                                                   const float* __restrict__ cw,
                                                   const float* __restrict__ cb,
                                                   u16* __restrict__ xcH,
                                                   u16* __restrict__ xcL) {
    int d = blockIdx.x * 256 + threadIdx.x;
    int l0 = blockIdx.y * 32;
    float4 w = reinterpret_cast<const float4*>(cw)[d];
    float b = cb[d];
    float p0 = 0.f, p1 = 0.f, p2 = 0.f;
    if (l0 > 0) {
        size_t o0 = (size_t)(l0 - 3) * DI + d;
        size_t o1 = (size_t)(l0 - 2) * DI + d;
        size_t o2 = (size_t)(l0 - 1) * DI + d;
        p0 = bf2f(xsH[o0]) + bf2f(xsL[o0]);
        p1 = bf2f(xsH[o1]) + bf2f(xsL[o1]);
        p2 = bf2f(xsH[o2]) + bf2f(xsL[o2]);
    }
    for (int l = l0; l < l0 + 32; ++l) {
        size_t o = (size_t)l * DI + d;
        float c = bf2f(xsH[o]) + bf2f(xsL[o]);
        float s = b;
        s = fmaf(p0, w.x, s);
        s = fmaf(p1, w.y, s);
        s = fmaf(p2, w.z, s);
        s = fmaf(c,  w.w, s);
        float v = s * sigmoidf_(s);
        u16 h = f2bf(v);
        xcH[o] = h;
        xcL[o] = f2bf(v - bf2f(h));
        p0 = p1; p1 = p2; p2 = c;
    }
}

// ---------------- Scan pass 1 ----------------
__global__ __launch_bounds__(256) void scan1_k(const float* __restrict__ delta,
                                               const u16* __restrict__ xcH,
                                               const u16* __restrict__ xcL,
                                               const float* __restrict__ bcd,
                                               const float* __restrict__ lmA,
                                               float* __restrict__ Pb,
                                               float* __restrict__ Sb) {
    __shared__ float Bs[LCHUNK][16];
    const int tid = threadIdx.x;
    const int d = (blockIdx.x * 256 + tid) >> 1;
    const int half = tid & 1;
    const int c = blockIdx.y;
    const int l0 = c * LCHUNK;
    {
        int row = tid >> 2, q = (tid & 3) * 4;
        float4 v = *reinterpret_cast<const float4*>(&bcd[(size_t)(l0 + row) * 96 + DRr + q]);
        *reinterpret_cast<float4*>(&Bs[row][q]) = v;
    }
    __syncthreads();
    float negA[8], h[8];
    #pragma unroll
    for (int j = 0; j < 8; j++) {
        negA[j] = -__expf(lmA[(size_t)d * Nst + half * 8 + j]);
        h[j] = 0.f;
    }
    float sdv = 0.f;
    for (int l = 0; l < LCHUNK; ++l) {
        size_t o = (size_t)(l0 + l) * DI + d;
        float dv = delta[o];
        float xcv = bf2f(xcH[o]) + bf2f(xcL[o]);
        sdv += dv;
        float dvx = dv * xcv;
        #pragma unroll
        for (int j = 0; j < 8; j++) {
            float a = __expf(dv * negA[j]);
            h[j] = fmaf(a, h[j], dvx * Bs[l][half * 8 + j]);
        }
    }
    size_t base = ((size_t)c * DI + d) * Nst + half * 8;
    #pragma unroll
    for (int j = 0; j < 8; j++) {
        Pb[base + j] = __expf(sdv * negA[j]);
        Sb[base + j] = h[j];
    }
}

// ---------------- Scan pass 2: combine in place (Pb -> Hinit) ----------------
__global__ __launch_bounds__(256) void scan2_k(float* __restrict__ PH,
                                               const float* __restrict__ Sb) {
    int t = blockIdx.x * 256 + threadIdx.x;
    float H = 0.f;
    for (int c = 0; c < NCHUNK; c++) {
        size_t idx = (size_t)c * (DI * Nst) + t;
        float P = PH[idx], S = Sb[idx];
        PH[idx] = H;
        H = S + P * H;
    }
}

// ---------------- Scan pass 3 ----------------
__global__ __launch_bounds__(256) void scan3_k(const float* __restrict__ delta,
                                               const u16* __restrict__ xcH,
                                               const u16* __restrict__ xcL,
                                               const float* __restrict__ bcd,
                                               const float* __restrict__ lmA,
                                               const float* __restrict__ Dp,
                                               const float* __restrict__ gate,
                                               const float* __restrict__ Hinit,
                                               u16* __restrict__ yH,
                                               u16* __restrict__ yL) {
    __shared__ float BCs[LCHUNK][32];
    const int tid = threadIdx.x;
    const int d = (blockIdx.x * 256 + tid) >> 1;
    const int half = tid & 1;
    const int c = blockIdx.y;
    const int l0 = c * LCHUNK;
    #pragma unroll
    for (int i = 0; i < 2; i++) {
        int idx = tid + 256 * i;
        int row = idx >> 3, q = (idx & 7) * 4;
        float4 v = *reinterpret_cast<const float4*>(&bcd[(size_t)(l0 + row) * 96 + DRr + q]);
        *reinterpret_cast<float4*>(&BCs[row][q]) = v;
    }
    __syncthreads();
    float negA[8], h[8];
    size_t hbase = ((size_t)c * DI + d) * Nst + half * 8;
    #pragma unroll
    for (int j = 0; j < 8; j++) {
        negA[j] = -__expf(lmA[(size_t)d * Nst + half * 8 + j]);
        h[j] = Hinit[hbase + j];
    }
    float Dpv = Dp[d];
    for (int l = 0; l < LCHUNK; ++l) {
        size_t o = (size_t)(l0 + l) * DI + d;
        float dv = delta[o];
        float xcv = bf2f(xcH[o]) + bf2f(xcL[o]);
        float dvx = dv * xcv;
        float yp = 0.f;
        #pragma unroll
        for (int j = 0; j < 8; j++) {
            float a = __expf(dv * negA[j]);
            h[j] = fmaf(a, h[j], dvx * BCs[l][half * 8 + j]);
            yp = fmaf(BCs[l][16 + half * 8 + j], h[j], yp);
        }
        yp += __shfl_xor(yp, 1);
        if (half == 0) {
            float yv = (yp + xcv * Dpv) * gate[o];
            u16 hq = f2bf(yv);
            yH[o] = hq;
            yL[o] = f2bf(yv - bf2f(hq));
        }
    }
}

extern "C" void kernel_launch(void* const* d_in, const int* in_sizes, int n_in,
                              void* d_out, int out_size, void* d_ws, size_t ws_size,
                              hipStream_t stream) {
    const float* x          = (const float*)d_in[0];
    const float* rms_w      = (const float*)d_in[1];
    const float* in_proj_w  = (const float*)d_in[2];
    const float* conv_w     = (const float*)d_in[3];
    const float* conv_b     = (const float*)d_in[4];
    const float* bcd_w      = (const float*)d_in[5];
    const float* dup_w      = (const float*)d_in[6];
    const float* dup_b      = (const float*)d_in[7];
    const float* lmA        = (const float*)d_in[8];
    const float* Dp         = (const float*)d_in[9];
    const float* out_proj_w = (const float*)d_in[10];
    float* out = (float*)d_out;
    char*  W   = (char*)d_ws;

    const size_t MB = 1ull << 20;
    const bool ext = ws_size >= 85 * MB;   // room for WoH/WoL at 77-85MB
    // Region A: 0-16MB  : WiH/WiL -> delta
    u16*   WiH  = (u16*)(W + 0);
    u16*   WiL  = (u16*)(W + 8 * MB);
    float* delta= (float*)(W + 0);
    // Region B: 16-32MB : xsH/xsL -> part(12) -> Sb(4) -> yH/yL(16)
    u16*   xsH  = (u16*)(W + 16 * MB);
    u16*   xsL  = (u16*)(W + 24 * MB);
    float* part = (float*)(W + 16 * MB);
    float* Sb   = (float*)(W + 16 * MB);
    u16*   yH   = (u16*)(W + 16 * MB);
    u16*   yL   = (u16*)(W + 24 * MB);
    // Region C+D: 32-64MB : gate(16) + xcH/xcL(16) -> opart (32MB, post-scan3)
    float* gate = (float*)(W + 32 * MB);
    u16*   xcH  = (u16*)(W + 48 * MB);
    u16*   xcL  = (u16*)(W + 56 * MB);
    float* opart= (float*)(W + 32 * MB);
    // Region E: 64-72MB : xnH/xnL -> WoH/WoL (fallback path only)
    u16*   xnH  = (u16*)(W + 64 * MB);
    u16*   xnL  = (u16*)(W + 68 * MB);
    // Region F: 72-77MB : bcd f32 (72-72.75) + small weights (73-74.75, dead by step 7)
    //                     + Pb (73-77, written by scan1)
    float* bcd  = (float*)(W + 72 * MB);
    u16*   bwTH = (u16*)(W + 73 * MB);
    u16*   bwTL = (u16*)(W + 73 * MB + 384 * 1024);
    u16*   dwTH = (u16*)(W + 73 * MB + 768 * 1024);
    u16*   dwTL = (u16*)(W + 73 * MB + 1024 * 1024);
    u16*   bcdH = (u16*)(W + 73 * MB + 1280 * 1024);
    u16*   bcdL = (u16*)(W + 73 * MB + 1536 * 1024);
    float* Pb   = (float*)(W + 73 * MB);
    // Wo split: extended at 77-85MB (prep1), else 64-72MB (after in_proj)
    u16*   WoH  = ext ? (u16*)(W + 77 * MB) : (u16*)(W + 64 * MB);
    u16*   WoL  = ext ? (u16*)(W + 81 * MB) : (u16*)(W + 68 * MB);

    // 1. fused prep: RMSNorm + Wi + bcd_w + dup_w (+Wo if ext)
    int nprep = 2048 + 4096 + 192 + 128 + (ext ? 2048 : 0);
    prep1_k<<<nprep, 256, 0, stream>>>(x, rms_w, xnH, xnL, in_proj_w, WiH, WiL,
                                       bcd_w, bwTH, bwTL, dup_w, dwTH, dwTL,
                                       out_proj_w, WoH, WoL);
    // 2. in_proj: xs (split bf16) / gate
    gemm_mfma3<128, 128, 4><<<dim3(4096 / 128, Lseq / 128), 256, 0, stream>>>(
        xnH, xnL, WiH, WiL, nullptr, gate, xsH, xsL, nullptr, Lseq, 2 * DI, Dmod);
    // 3. conv + silu -> xc split bf16
    conv_silu_k<<<dim3(DI / 256, Lseq / 32), 256, 0, stream>>>(xsH, xsL, conv_w, conv_b, xcH, xcL);
    // 3b. fallback: Wo prep after in_proj (xn dead)
    if (!ext) {
        wsplitT_k<<<dim3(1024 / 32, 2048 / 32), 256, 0, stream>>>(out_proj_w, 2048, 1024, WoH, WoL);
    }
    // 4. bcd = xc @ bcd_w (split-K MFMA + reduce)
    gemm_mfma3<128, 96, 5><<<dim3(1, Lseq / 128, SPLITK), 256, 0, stream>>>(
        xcH, xcL, bwTH, bwTL, part, nullptr, nullptr, nullptr, nullptr, Lseq, 96, DI);
    bcd_reduce_k<<<Lseq * 96 / 256, 256, 0, stream>>>(part, bcd, bcdH, bcdL);
    // 5. delta = softplus(bcd[:, :64] @ dup_w + dup_b)  (nt==2 fast path)
    gemm_mfma3<64, 128, 2><<<dim3(DI / 128, Lseq / 64), 256, 0, stream>>>(
        bcdH, bcdL, dwTH, dwTL, delta, nullptr, nullptr, nullptr, dup_b, Lseq, DI, DRr);
    // 6-8. chunked selective scan
    scan1_k<<<dim3(16, NCHUNK), 256, 0, stream>>>(delta, xcH, xcL, bcd, lmA, Pb, Sb);
    scan2_k<<<dim3(DI * Nst / 256), 256, 0, stream>>>(Pb, Sb);
    scan3_k<<<dim3(16, NCHUNK), 256, 0, stream>>>(delta, xcH, xcL, bcd, lmA, Dp, gate, Pb, yH, yL);
    // 9. out_proj: 128x128 + split-K=4, reduce + residual
    gemm_mfma3<128, 128, 5><<<dim3(Dmod / 128, Lseq / 128, OSPLIT), 256, 0, stream>>>(
        yH, yL, WoH, WoL, opart, nullptr, nullptr, nullptr, nullptr, Lseq, Dmod, DI);
    out_reduce_k<<<Lseq * Dmod / 1024, 256, 0, stream>>>(opart, x, out);
}

// Round 13
// 237.503 us; speedup vs baseline: 1.0356x; 1.0356x over previous
//
#include <hip/hip_runtime.h>
#include <hip/hip_bf16.h>
#include <math.h>

#define Lseq 2048
#define Dmod 1024
#define DI   2048
#define Nst  16
#define DRr  64
#define NCHUNK 32
#define LCHUNK 64
#define SPLITK 16
#define OSPLIT 4

typedef unsigned short u16;
typedef float  f32x4  __attribute__((ext_vector_type(4)));
typedef short  short8 __attribute__((ext_vector_type(8)));

__device__ __forceinline__ float sigmoidf_(float x) { return 1.f / (1.f + expf(-x)); }
__device__ __forceinline__ float softplusf_(float x) {
    return fmaxf(x, 0.f) + log1pf(expf(-fabsf(x)));
}
__device__ __forceinline__ u16 f2bf(float x) {
    union { float f; unsigned u; } v; v.f = x;
    unsigned r = (v.u + 0x7fffu + ((v.u >> 16) & 1u)) >> 16;
    return (u16)r;
}
__device__ __forceinline__ float bf2f(u16 h) {
    union { unsigned u; float f; } v; v.u = ((unsigned)h) << 16; return v.f;
}
__device__ __forceinline__ void async16(const void* g, void* l) {
    __builtin_amdgcn_global_load_lds((__attribute__((address_space(1))) void*)g,
                                     (__attribute__((address_space(3))) void*)l, 16, 0, 0);
}

struct __align__(8) u16x4 { u16 x, y, z, w; };

// ---------------- Weight transpose + split body ----------------
__device__ __forceinline__ void wsplit_body(const float* __restrict__ W, int R, int Cn,
                                            int bx, int by, float (*t)[33],
                                            u16* __restrict__ Th, u16* __restrict__ Tl) {
    int r0 = by * 32, c0 = bx * 32;
    int tr = threadIdx.x >> 3;
    int tc4 = (threadIdx.x & 7) * 4;
    float4 v = *reinterpret_cast<const float4*>(&W[(size_t)(r0 + tr) * Cn + c0 + tc4]);
    t[tr][tc4 + 0] = v.x; t[tr][tc4 + 1] = v.y;
    t[tr][tc4 + 2] = v.z; t[tr][tc4 + 3] = v.w;
    __syncthreads();
    u16x4 H, L;
    u16* hp = &H.x; u16* lp = &L.x;
    #pragma unroll
    for (int q = 0; q < 4; q++) {
        float xv = t[tc4 + q][tr];
        u16 h = f2bf(xv); hp[q] = h; lp[q] = f2bf(xv - bf2f(h));
    }
    size_t o = (size_t)(c0 + tr) * R + r0 + tc4;
    *reinterpret_cast<u16x4*>(&Th[o]) = H;
    *reinterpret_cast<u16x4*>(&Tl[o]) = L;
}

// ---------------- prep1: rmsnorm rows (b<2048) + in_proj_w transpose (b>=2048) ------
__global__ __launch_bounds__(256) void prep1_k(const float* __restrict__ x,
                                               const float* __restrict__ rms_w,
                                               u16* __restrict__ xnH, u16* __restrict__ xnL,
                                               const float* __restrict__ Wi,
                                               u16* __restrict__ WiH, u16* __restrict__ WiL) {
    __shared__ float t[32][33];
    __shared__ float s4[4];
    int b = blockIdx.x;
    if (b < 2048) {
        int row = b, tid = threadIdx.x;
        float4 v = reinterpret_cast<const float4*>(x + (size_t)row * Dmod)[tid];
        float ss = v.x * v.x + v.y * v.y + v.z * v.z + v.w * v.w;
        #pragma unroll
        for (int m = 32; m >= 1; m >>= 1) ss += __shfl_xor(ss, m);
        if ((tid & 63) == 0) s4[tid >> 6] = ss;
        __syncthreads();
        float tot = s4[0] + s4[1] + s4[2] + s4[3];
        float scale = rsqrtf(tot * (1.0f / Dmod) + 1e-5f);
        float4 wv = reinterpret_cast<const float4*>(rms_w)[tid];
        float o[4] = {v.x * scale * wv.x, v.y * scale * wv.y,
                      v.z * scale * wv.z, v.w * scale * wv.w};
        u16x4 H, L;
        u16* hp = &H.x; u16* lp = &L.x;
        #pragma unroll
        for (int q = 0; q < 4; q++) {
            u16 h = f2bf(o[q]); hp[q] = h; lp[q] = f2bf(o[q] - bf2f(h));
        }
        reinterpret_cast<u16x4*>(xnH + (size_t)row * Dmod)[tid] = H;
        reinterpret_cast<u16x4*>(xnL + (size_t)row * Dmod)[tid] = L;
    } else {
        int bb = b - 2048;                 // in_proj_w: (1024 x 4096), grid (128 x 32)
        wsplit_body(Wi, 1024, 4096, bb & 127, bb >> 7, t, WiH, WiL);
    }
}

// Combined prep for out_proj_w (2048 blk), bcd_w (192 blk), dup_w (128 blk)
__global__ __launch_bounds__(256) void wsplit3_k(const float* __restrict__ Wo,
                                                 const float* __restrict__ Wb,
                                                 const float* __restrict__ Wd,
                                                 u16* WoH, u16* WoL,
                                                 u16* bwTH, u16* bwTL,
                                                 u16* dwTH, u16* dwTL) {
    __shared__ float t[32][33];
    int b = blockIdx.x;
    if (b < 2048) {
        wsplit_body(Wo, 2048, 1024, b & 31, b >> 5, t, WoH, WoL);
    } else if (b < 2240) {
        int bb = b - 2048;
        wsplit_body(Wb, 2048, 96, bb % 3, bb / 3, t, bwTH, bwTL);
    } else {
        int bb = b - 2240;
        wsplit_body(Wd, 64, 2048, bb & 63, bb >> 6, t, dwTH, dwTL);
    }
}

// ---------------- Split-bf16 MFMA GEMM (R9/R11 single-barrier pipeline, swizzled) ---
// C[M][N] = A[M][K] @ Bt[N][K]^T
// EPI: 2 C=softplus(acc+aux[col]); 4 dual in_proj (cols<DI -> U1/U2 split bf16,
//      cols>=DI -> C2=silu); 5 split-K partial write to C.
// FAST (compile-time): K fits in 2 BK-tiles -> stage both once, no mid-loop sync.
template <int BM, int BN, int EPI, bool FAST = false>
__global__ __launch_bounds__(256) void gemm_mfma3(
    const u16* __restrict__ Ah, const u16* __restrict__ Al,
    const u16* __restrict__ Bh, const u16* __restrict__ Bl,
    float* __restrict__ C, float* __restrict__ C2,
    u16* __restrict__ U1, u16* __restrict__ U2,
    const float* __restrict__ aux,
    int M, int N, int K) {
    constexpr int BK = 32;
    constexpr int MF = BM / 32, NF = BN / 32;
    constexpr int CH_A = BM / 16, CH_B = BN / 16;
    __shared__ u16 AhT[2][BM][BK], AlT[2][BM][BK], BhT[2][BN][BK], BlT[2][BN][BK];
    const int tid = threadIdx.x, lane = tid & 63, wid = tid >> 6;
    const int wr = wid >> 1, wc = wid & 1;
    const int lr = lane & 15;
    const int sw = (lane >> 1) & 3;
    const int lkq = ((lane >> 4) ^ sw) * 8;              // swizzled read col-block
    const int bm0 = blockIdx.y * BM, bn0 = blockIdx.x * BN;
    const int srow = lane >> 2;
    const int scol_ = ((lane & 3) ^ ((lane >> 3) & 3)) * 8;   // pre-swizzled source col

    int kbeg = 0, kend = K;
    if (EPI == 5) {
        int ks = K / gridDim.z;
        kbeg = blockIdx.z * ks;
        kend = kbeg + ks;
    }
    const int nt = (kend - kbeg) / BK;

    auto STAGE = [&](int buf, int k0) {
        int ci = 0;
        #pragma unroll
        for (int c = 0; c < CH_A; c++, ci++) if ((ci & 3) == wid) {
            size_t g = (size_t)(bm0 + c * 16 + srow) * K + (k0 + scol_);
            async16(Ah + g, (u16*)&AhT[buf][0][0] + c * 512 + lane * 8);
        }
        #pragma unroll
        for (int c = 0; c < CH_A; c++, ci++) if ((ci & 3) == wid) {
            size_t g = (size_t)(bm0 + c * 16 + srow) * K + (k0 + scol_);
            async16(Al + g, (u16*)&AlT[buf][0][0] + c * 512 + lane * 8);
        }
        #pragma unroll
        for (int c = 0; c < CH_B; c++, ci++) if ((ci & 3) == wid) {
            size_t g = (size_t)(bn0 + c * 16 + srow) * K + (k0 + scol_);
            async16(Bh + g, (u16*)&BhT[buf][0][0] + c * 512 + lane * 8);
        }
        #pragma unroll
        for (int c = 0; c < CH_B; c++, ci++) if ((ci & 3) == wid) {
            size_t g = (size_t)(bn0 + c * 16 + srow) * K + (k0 + scol_);
            async16(Bl + g, (u16*)&BlT[buf][0][0] + c * 512 + lane * 8);
        }
    };

    f32x4 acc[MF][NF];
    #pragma unroll
    for (int i = 0; i < MF; i++)
        #pragma unroll
        for (int j = 0; j < NF; j++) acc[i][j] = (f32x4){0.f, 0.f, 0.f, 0.f};

    if constexpr (FAST) {
        // K <= 2*BK: stage both tiles once, single wait+barrier, no LDS rewrite
        STAGE(0, kbeg);
        if (nt > 1) STAGE(1, kbeg + BK);
        asm volatile("s_waitcnt vmcnt(0)" ::: "memory");
        __builtin_amdgcn_s_barrier();
        #pragma unroll
        for (int t = 0; t < 2; ++t) {
            if (t == 1 && nt < 2) break;
            short8 ah[MF], al[MF], bh[NF], bl[NF];
            #pragma unroll
            for (int i = 0; i < MF; i++) {
                int r = wr * (MF * 16) + i * 16 + lr;
                ah[i] = *(const short8*)&AhT[t][r][lkq];
                al[i] = *(const short8*)&AlT[t][r][lkq];
            }
            #pragma unroll
            for (int j = 0; j < NF; j++) {
                int r = wc * (NF * 16) + j * 16 + lr;
                bh[j] = *(const short8*)&BhT[t][r][lkq];
                bl[j] = *(const short8*)&BlT[t][r][lkq];
            }
            asm volatile("s_waitcnt lgkmcnt(0)" ::: "memory");
            __builtin_amdgcn_sched_barrier(0);
            #pragma unroll
            for (int i = 0; i < MF; i++)
                #pragma unroll
                for (int j = 0; j < NF; j++) {
                    acc[i][j] = __builtin_amdgcn_mfma_f32_16x16x32_bf16(ah[i], bh[j], acc[i][j], 0, 0, 0);
                    acc[i][j] = __builtin_amdgcn_mfma_f32_16x16x32_bf16(ah[i], bl[j], acc[i][j], 0, 0, 0);
                    acc[i][j] = __builtin_amdgcn_mfma_f32_16x16x32_bf16(al[i], bh[j], acc[i][j], 0, 0, 0);
                }
        }
    } else {
        // prologue: fill buffer 0
        STAGE(0, kbeg);
        asm volatile("s_waitcnt vmcnt(0)" ::: "memory");
        __builtin_amdgcn_s_barrier();

        for (int t = 0; t < nt; ++t) {
            const int cur = t & 1;
            // issue next tile's loads first — they fly under this tile's ds_read+MFMA
            if (t + 1 < nt) STAGE(cur ^ 1, kbeg + (t + 1) * BK);

            short8 ah[MF], al[MF], bh[NF], bl[NF];
            #pragma unroll
            for (int i = 0; i < MF; i++) {
                int r = wr * (MF * 16) + i * 16 + lr;
                ah[i] = *(const short8*)&AhT[cur][r][lkq];
                al[i] = *(const short8*)&AlT[cur][r][lkq];
            }
            #pragma unroll
            for (int j = 0; j < NF; j++) {
                int r = wc * (NF * 16) + j * 16 + lr;
                bh[j] = *(const short8*)&BhT[cur][r][lkq];
                bl[j] = *(const short8*)&BlT[cur][r][lkq];
            }
            asm volatile("s_waitcnt lgkmcnt(0)" ::: "memory");
            __builtin_amdgcn_sched_barrier(0);
            __builtin_amdgcn_s_setprio(1);
            #pragma unroll
            for (int i = 0; i < MF; i++)
                #pragma unroll
                for (int j = 0; j < NF; j++) {
                    acc[i][j] = __builtin_amdgcn_mfma_f32_16x16x32_bf16(ah[i], bh[j], acc[i][j], 0, 0, 0);
                    acc[i][j] = __builtin_amdgcn_mfma_f32_16x16x32_bf16(ah[i], bl[j], acc[i][j], 0, 0, 0);
                    acc[i][j] = __builtin_amdgcn_mfma_f32_16x16x32_bf16(al[i], bh[j], acc[i][j], 0, 0, 0);
                }
            __builtin_amdgcn_s_setprio(0);
            if (t + 1 < nt) {
                // next buffer staged (own loads landed) + all waves done reading cur
                asm volatile("s_waitcnt vmcnt(0)" ::: "memory");
                __builtin_amdgcn_s_barrier();
            }
        }
    }

    float* Cp = C;
    if (EPI == 5) Cp = C + (size_t)blockIdx.z * M * N;
    #pragma unroll
    for (int i = 0; i < MF; i++)
        #pragma unroll
        for (int j = 0; j < NF; j++) {
            int rowg = bm0 + wr * (MF * 16) + i * 16 + (lane >> 4) * 4;
            int colg = bn0 + wc * (NF * 16) + j * 16 + lr;
            #pragma unroll
            for (int q = 0; q < 4; q++) {
                float v = acc[i][j][q];
                if (EPI == 5) {
                    Cp[(size_t)(rowg + q) * N + colg] = v;
                } else if (EPI == 2) {
                    C[(size_t)(rowg + q) * N + colg] = softplusf_(v + aux[colg]);
                } else if (EPI == 4) {
                    if (colg < DI) {
                        size_t o = (size_t)(rowg + q) * DI + colg;
                        u16 hh = f2bf(v);
                        U1[o] = hh;
                        U2[o] = f2bf(v - bf2f(hh));
                    } else {
                        C2[(size_t)(rowg + q) * DI + (colg - DI)] = v * sigmoidf_(v);
                    }
                }
            }
        }
}

// ---------------- bcd split-K reduce ----------------
__global__ __launch_bounds__(256) void bcd_reduce_k(const float* __restrict__ partial,
                                                    float* __restrict__ bcd,
                                                    u16* __restrict__ bH,
                                                    u16* __restrict__ bL) {
    const int NT = Lseq * 96;
    int t = blockIdx.x * 256 + threadIdx.x;
    float s = 0.f;
    #pragma unroll
    for (int z = 0; z < SPLITK; z++) s += partial[(size_t)z * NT + t];
    bcd[t] = s;
    int col = t % 96, row = t / 96;
    if (col < DRr) {
        u16 h = f2bf(s);
        bH[(size_t)row * DRr + col] = h;
        bL[(size_t)row * DRr + col] = f2bf(s - bf2f(h));
    }
}

// ---------------- out split-K=4 reduce + residual ----------------
__global__ __launch_bounds__(256) void out_reduce_k(const float* __restrict__ part,
                                                    const float* __restrict__ x,
                                                    float* __restrict__ out) {
    int t = blockIdx.x * 256 + threadIdx.x;
    const size_t NT = (size_t)Lseq * Dmod;
    float4 xv = reinterpret_cast<const float4*>(x)[t];
    float4 o = xv;
    #pragma unroll
    for (int z = 0; z < OSPLIT; z++) {
        float4 p = reinterpret_cast<const float4*>(part + (size_t)z * NT)[t];
        o.x += p.x; o.y += p.y; o.z += p.z; o.w += p.w;
    }
    reinterpret_cast<float4*>(out)[t] = o;
}

// ---------------- Conv1d(K=4)+SiLU, rolling window, split-bf16 in/out ----------
__global__ __launch_bounds__(256) void conv_silu_k(const u16* __restrict__ xsH,
                                                   const u16* __restrict__ xsL,
                                                   const float* __restrict__ cw,
                                                   const float* __restrict__ cb,
                                                   u16* __restrict__ xcH,
                                                   u16* __restrict__ xcL) {
    int d = blockIdx.x * 256 + threadIdx.x;
    int l0 = blockIdx.y * 32;
    float4 w = reinterpret_cast<const float4*>(cw)[d];
    float b = cb[d];
    float p0 = 0.f, p1 = 0.f, p2 = 0.f;
    if (l0 > 0) {
        size_t o0 = (size_t)(l0 - 3) * DI + d;
        size_t o1 = (size_t)(l0 - 2) * DI + d;
        size_t o2 = (size_t)(l0 - 1) * DI + d;
        p0 = bf2f(xsH[o0]) + bf2f(xsL[o0]);
        p1 = bf2f(xsH[o1]) + bf2f(xsL[o1]);
        p2 = bf2f(xsH[o2]) + bf2f(xsL[o2]);
    }
    for (int l = l0; l < l0 + 32; ++l) {
        size_t o = (size_t)l * DI + d;
        float c = bf2f(xsH[o]) + bf2f(xsL[o]);
        float s = b;
        s = fmaf(p0, w.x, s);
        s = fmaf(p1, w.y, s);
        s = fmaf(p2, w.z, s);
        s = fmaf(c,  w.w, s);
        float v = s * sigmoidf_(s);
        u16 h = f2bf(v);
        xcH[o] = h;
        xcL[o] = f2bf(v - bf2f(h));
        p0 = p1; p1 = p2; p2 = c;
    }
}

// ---------------- Scan pass 1 ----------------
__global__ __launch_bounds__(256) void scan1_k(const float* __restrict__ delta,
                                               const u16* __restrict__ xcH,
                                               const u16* __restrict__ xcL,
                                               const float* __restrict__ bcd,
                                               const float* __restrict__ lmA,
                                               float* __restrict__ Pb,
                                               float* __restrict__ Sb) {
    __shared__ float Bs[LCHUNK][16];
    const int tid = threadIdx.x;
    const int d = (blockIdx.x * 256 + tid) >> 1;
    const int half = tid & 1;
    const int c = blockIdx.y;
    const int l0 = c * LCHUNK;
    {
        int row = tid >> 2, q = (tid & 3) * 4;
        float4 v = *reinterpret_cast<const float4*>(&bcd[(size_t)(l0 + row) * 96 + DRr + q]);
        *reinterpret_cast<float4*>(&Bs[row][q]) = v;
    }
    __syncthreads();
    float negA[8], h[8];
    #pragma unroll
    for (int j = 0; j < 8; j++) {
        negA[j] = -__expf(lmA[(size_t)d * Nst + half * 8 + j]);
        h[j] = 0.f;
    }
    float sdv = 0.f;
    for (int l = 0; l < LCHUNK; ++l) {
        size_t o = (size_t)(l0 + l) * DI + d;
        float dv = delta[o];
        float xcv = bf2f(xcH[o]) + bf2f(xcL[o]);
        sdv += dv;
        float dvx = dv * xcv;
        #pragma unroll
        for (int j = 0; j < 8; j++) {
            float a = __expf(dv * negA[j]);
            h[j] = fmaf(a, h[j], dvx * Bs[l][half * 8 + j]);
        }
    }
    size_t base = ((size_t)c * DI + d) * Nst + half * 8;
    #pragma unroll
    for (int j = 0; j < 8; j++) {
        Pb[base + j] = __expf(sdv * negA[j]);
        Sb[base + j] = h[j];
    }
}

// ---------------- Scan pass 2: combine in place (Pb -> Hinit) ----------------
__global__ __launch_bounds__(256) void scan2_k(float* __restrict__ PH,
                                               const float* __restrict__ Sb) {
    int t = blockIdx.x * 256 + threadIdx.x;
    float H = 0.f;
    for (int c = 0; c < NCHUNK; c++) {
        size_t idx = (size_t)c * (DI * Nst) + t;
        float P = PH[idx], S = Sb[idx];
        PH[idx] = H;
        H = S + P * H;
    }
}

// ---------------- Scan pass 3 ----------------
__global__ __launch_bounds__(256) void scan3_k(const float* __restrict__ delta,
                                               const u16* __restrict__ xcH,
                                               const u16* __restrict__ xcL,
                                               const float* __restrict__ bcd,
                                               const float* __restrict__ lmA,
                                               const float* __restrict__ Dp,
                                               const float* __restrict__ gate,
                                               const float* __restrict__ Hinit,
                                               u16* __restrict__ yH,
                                               u16* __restrict__ yL) {
    __shared__ float BCs[LCHUNK][32];
    const int tid = threadIdx.x;
    const int d = (blockIdx.x * 256 + tid) >> 1;
    const int half = tid & 1;
    const int c = blockIdx.y;
    const int l0 = c * LCHUNK;
    #pragma unroll
    for (int i = 0; i < 2; i++) {
        int idx = tid + 256 * i;
        int row = idx >> 3, q = (idx & 7) * 4;
        float4 v = *reinterpret_cast<const float4*>(&bcd[(size_t)(l0 + row) * 96 + DRr + q]);
        *reinterpret_cast<float4*>(&BCs[row][q]) = v;
    }
    __syncthreads();
    float negA[8], h[8];
    size_t hbase = ((size_t)c * DI + d) * Nst + half * 8;
    #pragma unroll
    for (int j = 0; j < 8; j++) {
        negA[j] = -__expf(lmA[(size_t)d * Nst + half * 8 + j]);
        h[j] = Hinit[hbase + j];
    }
    float Dpv = Dp[d];
    for (int l = 0; l < LCHUNK; ++l) {
        size_t o = (size_t)(l0 + l) * DI + d;
        float dv = delta[o];
        float xcv = bf2f(xcH[o]) + bf2f(xcL[o]);
        float dvx = dv * xcv;
        float yp = 0.f;
        #pragma unroll
        for (int j = 0; j < 8; j++) {
            float a = __expf(dv * negA[j]);
            h[j] = fmaf(a, h[j], dvx * BCs[l][half * 8 + j]);
            yp = fmaf(BCs[l][16 + half * 8 + j], h[j], yp);
        }
        yp += __shfl_xor(yp, 1);
        if (half == 0) {
            float yv = (yp + xcv * Dpv) * gate[o];
            u16 hq = f2bf(yv);
            yH[o] = hq;
            yL[o] = f2bf(yv - bf2f(hq));
        }
    }
}

extern "C" void kernel_launch(void* const* d_in, const int* in_sizes, int n_in,
                              void* d_out, int out_size, void* d_ws, size_t ws_size,
                              hipStream_t stream) {
    const float* x          = (const float*)d_in[0];
    const float* rms_w      = (const float*)d_in[1];
    const float* in_proj_w  = (const float*)d_in[2];
    const float* conv_w     = (const float*)d_in[3];
    const float* conv_b     = (const float*)d_in[4];
    const float* bcd_w      = (const float*)d_in[5];
    const float* dup_w      = (const float*)d_in[6];
    const float* dup_b      = (const float*)d_in[7];
    const float* lmA        = (const float*)d_in[8];
    const float* Dp         = (const float*)d_in[9];
    const float* out_proj_w = (const float*)d_in[10];
    float* out = (float*)d_out;
    char*  W   = (char*)d_ws;

    const size_t MB = 1ull << 20;
    // Region A: 0-16MB  : WiH/WiL -> delta
    u16*   WiH  = (u16*)(W + 0);
    u16*   WiL  = (u16*)(W + 8 * MB);
    float* delta= (float*)(W + 0);
    // Region B: 16-32MB : xsH/xsL -> {part(12)+small wts} -> Sb(4) -> yH/yL(16)
    u16*   xsH  = (u16*)(W + 16 * MB);
    u16*   xsL  = (u16*)(W + 24 * MB);
    float* part = (float*)(W + 16 * MB);
    u16*   bwTH = (u16*)(W + 28 * MB);
    u16*   bwTL = (u16*)(W + 28 * MB + 384 * 1024);
    u16*   dwTH = (u16*)(W + 28 * MB + 768 * 1024);
    u16*   dwTL = (u16*)(W + 28 * MB + 1024 * 1024);
    u16*   bcdH = (u16*)(W + 28 * MB + 1280 * 1024);
    u16*   bcdL = (u16*)(W + 28 * MB + 1536 * 1024);
    float* Sb   = (float*)(W + 16 * MB);
    u16*   yH   = (u16*)(W + 16 * MB);
    u16*   yL   = (u16*)(W + 24 * MB);
    // Region C+D: 32-64MB : gate(16) + xcH/xcL(16) -> opart (32MB, post-scan3)
    float* gate = (float*)(W + 32 * MB);
    u16*   xcH  = (u16*)(W + 48 * MB);
    u16*   xcL  = (u16*)(W + 56 * MB);
    float* opart= (float*)(W + 32 * MB);
    // Region E: 64-72MB : xnH/xnL -> WoH/WoL
    u16*   xnH  = (u16*)(W + 64 * MB);
    u16*   xnL  = (u16*)(W + 68 * MB);
    u16*   WoH  = (u16*)(W + 64 * MB);
    u16*   WoL  = (u16*)(W + 68 * MB);
    // Region F: 72-77MB : bcd f32 + Pb (becomes Hinit)
    float* bcd  = (float*)(W + 72 * MB);
    float* Pb   = (float*)(W + 73 * MB);

    // 1. fused: RMSNorm + in_proj_w transpose/split
    prep1_k<<<2048 + 4096, 256, 0, stream>>>(x, rms_w, xnH, xnL, in_proj_w, WiH, WiL);
    // 2. in_proj: xs (split bf16) / gate  (128x128, R11 pipeline)
    gemm_mfma3<128, 128, 4><<<dim3(4096 / 128, Lseq / 128), 256, 0, stream>>>(
        xnH, xnL, WiH, WiL, nullptr, gate, xsH, xsL, nullptr, Lseq, 2 * DI, Dmod);
    // 3. conv + silu -> xc split bf16 (rolling window, split input)
    conv_silu_k<<<dim3(DI / 256, Lseq / 32), 256, 0, stream>>>(xsH, xsL, conv_w, conv_b, xcH, xcL);
    // 4. combined prep: out_proj_w / bcd_w / dup_w (xn dead)
    wsplit3_k<<<2368, 256, 0, stream>>>(out_proj_w, bcd_w, dup_w,
                                        WoH, WoL, bwTH, bwTL, dwTH, dwTL);
    // 5. bcd = xc @ bcd_w (split-K MFMA + reduce)
    gemm_mfma3<128, 96, 5><<<dim3(1, Lseq / 128, SPLITK), 256, 0, stream>>>(
        xcH, xcL, bwTH, bwTL, part, nullptr, nullptr, nullptr, nullptr, Lseq, 96, DI);
    bcd_reduce_k<<<Lseq * 96 / 256, 256, 0, stream>>>(part, bcd, bcdH, bcdL);
    // 6. delta = softplus(bcd[:, :64] @ dup_w + dup_b)  (compile-time FAST: nt==2)
    gemm_mfma3<64, 128, 2, true><<<dim3(DI / 128, Lseq / 64), 256, 0, stream>>>(
        bcdH, bcdL, dwTH, dwTL, delta, nullptr, nullptr, nullptr, dup_b, Lseq, DI, DRr);
    // 7-9. chunked selective scan
    scan1_k<<<dim3(16, NCHUNK), 256, 0, stream>>>(delta, xcH, xcL, bcd, lmA, Pb, Sb);
    scan2_k<<<dim3(DI * Nst / 256), 256, 0, stream>>>(Pb, Sb);
    scan3_k<<<dim3(16, NCHUNK), 256, 0, stream>>>(delta, xcH, xcL, bcd, lmA, Dp, gate, Pb, yH, yL);
    // 10. out_proj: 128x128 + split-K=4, reduce + residual
    gemm_mfma3<128, 128, 5><<<dim3(Dmod / 128, Lseq / 128, OSPLIT), 256, 0, stream>>>(
        yH, yL, WoH, WoL, opart, nullptr, nullptr, nullptr, nullptr, Lseq, Dmod, DI);
    out_reduce_k<<<Lseq * Dmod / 1024, 256, 0, stream>>>(opart, x, out);
}

// Round 15
// 235.470 us; speedup vs baseline: 1.0446x; 1.0086x over previous
//
#include <hip/hip_runtime.h>
#include <hip/hip_bf16.h>
#include <math.h>

#define Lseq 2048
#define Dmod 1024
#define DI   2048
#define Nst  16
#define DRr  64
#define NCHUNK 32
#define LCHUNK 64
#define SPLITK 16
#define OSPLIT 4

typedef unsigned short u16;
typedef float  f32x4  __attribute__((ext_vector_type(4)));
typedef short  short8 __attribute__((ext_vector_type(8)));

__device__ __forceinline__ float sigmoidf_(float x) { return 1.f / (1.f + expf(-x)); }
__device__ __forceinline__ float softplusf_(float x) {
    return fmaxf(x, 0.f) + log1pf(expf(-fabsf(x)));
}
__device__ __forceinline__ u16 f2bf(float x) {
    union { float f; unsigned u; } v; v.f = x;
    unsigned r = (v.u + 0x7fffu + ((v.u >> 16) & 1u)) >> 16;
    return (u16)r;
}
__device__ __forceinline__ float bf2f(u16 h) {
    union { unsigned u; float f; } v; v.u = ((unsigned)h) << 16; return v.f;
}
__device__ __forceinline__ void async16(const void* g, void* l) {
    __builtin_amdgcn_global_load_lds((__attribute__((address_space(1))) void*)g,
                                     (__attribute__((address_space(3))) void*)l, 16, 0, 0);
}

struct __align__(8) u16x4 { u16 x, y, z, w; };

// ---------------- Weight transpose + split body ----------------
__device__ __forceinline__ void wsplit_body(const float* __restrict__ W, int R, int Cn,
                                            int bx, int by, float (*t)[33],
                                            u16* __restrict__ Th, u16* __restrict__ Tl) {
    int r0 = by * 32, c0 = bx * 32;
    int tr = threadIdx.x >> 3;
    int tc4 = (threadIdx.x & 7) * 4;
    float4 v = *reinterpret_cast<const float4*>(&W[(size_t)(r0 + tr) * Cn + c0 + tc4]);
    t[tr][tc4 + 0] = v.x; t[tr][tc4 + 1] = v.y;
    t[tr][tc4 + 2] = v.z; t[tr][tc4 + 3] = v.w;
    __syncthreads();
    u16x4 H, L;
    u16* hp = &H.x; u16* lp = &L.x;
    #pragma unroll
    for (int q = 0; q < 4; q++) {
        float xv = t[tc4 + q][tr];
        u16 h = f2bf(xv); hp[q] = h; lp[q] = f2bf(xv - bf2f(h));
    }
    size_t o = (size_t)(c0 + tr) * R + r0 + tc4;
    *reinterpret_cast<u16x4*>(&Th[o]) = H;
    *reinterpret_cast<u16x4*>(&Tl[o]) = L;
}

// ---------------- prep1: rmsnorm rows (b<2048) + in_proj_w transpose (b>=2048) ------
__global__ __launch_bounds__(256) void prep1_k(const float* __restrict__ x,
                                               const float* __restrict__ rms_w,
                                               u16* __restrict__ xnH, u16* __restrict__ xnL,
                                               const float* __restrict__ Wi,
                                               u16* __restrict__ WiH, u16* __restrict__ WiL) {
    __shared__ float t[32][33];
    __shared__ float s4[4];
    int b = blockIdx.x;
    if (b < 2048) {
        int row = b, tid = threadIdx.x;
        float4 v = reinterpret_cast<const float4*>(x + (size_t)row * Dmod)[tid];
        float ss = v.x * v.x + v.y * v.y + v.z * v.z + v.w * v.w;
        #pragma unroll
        for (int m = 32; m >= 1; m >>= 1) ss += __shfl_xor(ss, m);
        if ((tid & 63) == 0) s4[tid >> 6] = ss;
        __syncthreads();
        float tot = s4[0] + s4[1] + s4[2] + s4[3];
        float scale = rsqrtf(tot * (1.0f / Dmod) + 1e-5f);
        float4 wv = reinterpret_cast<const float4*>(rms_w)[tid];
        float o[4] = {v.x * scale * wv.x, v.y * scale * wv.y,
                      v.z * scale * wv.z, v.w * scale * wv.w};
        u16x4 H, L;
        u16* hp = &H.x; u16* lp = &L.x;
        #pragma unroll
        for (int q = 0; q < 4; q++) {
            u16 h = f2bf(o[q]); hp[q] = h; lp[q] = f2bf(o[q] - bf2f(h));
        }
        reinterpret_cast<u16x4*>(xnH + (size_t)row * Dmod)[tid] = H;
        reinterpret_cast<u16x4*>(xnL + (size_t)row * Dmod)[tid] = L;
    } else {
        int bb = b - 2048;                 // in_proj_w: (1024 x 4096), grid (128 x 32)
        wsplit_body(Wi, 1024, 4096, bb & 127, bb >> 7, t, WiH, WiL);
    }
}

// ---------------- mid: conv+silu (b<512) + out_proj/bcd/dup weight prep (b>=512) ----
// NOTE: weight outputs live at 73MB+ (region F) — disjoint from xsH/xsL (16-32MB),
// so the concurrent conv reads are safe (R14's bug was bwT* aliasing xsL).
__global__ __launch_bounds__(256) void mid_k(const u16* __restrict__ xsH,
                                             const u16* __restrict__ xsL,
                                             const float* __restrict__ cw,
                                             const float* __restrict__ cb,
                                             u16* __restrict__ xcH,
                                             u16* __restrict__ xcL,
                                             const float* __restrict__ Wo,
                                             const float* __restrict__ Wb,
                                             const float* __restrict__ Wd,
                                             u16* WoH, u16* WoL,
                                             u16* bwTH, u16* bwTL,
                                             u16* dwTH, u16* dwTL) {
    int b = blockIdx.x;
    if (b < 512) {
        // conv: original grid (8, 64): x = d-block 0..7, y = l-block 0..63
        int d = (b & 7) * 256 + threadIdx.x;
        int l0 = (b >> 3) * 32;
        float4 w = reinterpret_cast<const float4*>(cw)[d];
        float bb = cb[d];
        float p0 = 0.f, p1 = 0.f, p2 = 0.f;
        if (l0 > 0) {
            size_t o0 = (size_t)(l0 - 3) * DI + d;
            size_t o1 = (size_t)(l0 - 2) * DI + d;
            size_t o2 = (size_t)(l0 - 1) * DI + d;
            p0 = bf2f(xsH[o0]) + bf2f(xsL[o0]);
            p1 = bf2f(xsH[o1]) + bf2f(xsL[o1]);
            p2 = bf2f(xsH[o2]) + bf2f(xsL[o2]);
        }
        for (int l = l0; l < l0 + 32; ++l) {
            size_t o = (size_t)l * DI + d;
            float c = bf2f(xsH[o]) + bf2f(xsL[o]);
            float s = bb;
            s = fmaf(p0, w.x, s);
            s = fmaf(p1, w.y, s);
            s = fmaf(p2, w.z, s);
            s = fmaf(c,  w.w, s);
            float v = s * sigmoidf_(s);
            u16 h = f2bf(v);
            xcH[o] = h;
            xcL[o] = f2bf(v - bf2f(h));
            p0 = p1; p1 = p2; p2 = c;
        }
    } else {
        __shared__ float t[32][33];
        int bb = b - 512;
        if (bb < 2048) {
            wsplit_body(Wo, 2048, 1024, bb & 31, bb >> 5, t, WoH, WoL);
        } else if (bb < 2240) {
            int b2 = bb - 2048;
            wsplit_body(Wb, 2048, 96, b2 % 3, b2 / 3, t, bwTH, bwTL);
        } else {
            int b2 = bb - 2240;
            wsplit_body(Wd, 64, 2048, b2 & 63, b2 >> 6, t, dwTH, dwTL);
        }
    }
}

// ---------------- Split-bf16 MFMA GEMM (R9/R11 single-barrier pipeline, swizzled) ---
// C[M][N] = A[M][K] @ Bt[N][K]^T
// EPI: 2 C=softplus(acc+aux[col]); 4 dual in_proj (cols<DI -> U1/U2 split bf16,
//      cols>=DI -> C2=silu); 5 split-K partial write to C.
// FAST (compile-time): K fits in 2 BK-tiles -> stage both once, no mid-loop sync.
template <int BM, int BN, int EPI, bool FAST = false>
__global__ __launch_bounds__(256) void gemm_mfma3(
    const u16* __restrict__ Ah, const u16* __restrict__ Al,
    const u16* __restrict__ Bh, const u16* __restrict__ Bl,
    float* __restrict__ C, float* __restrict__ C2,
    u16* __restrict__ U1, u16* __restrict__ U2,
    const float* __restrict__ aux,
    int M, int N, int K) {
    constexpr int BK = 32;
    constexpr int MF = BM / 32, NF = BN / 32;
    constexpr int CH_A = BM / 16, CH_B = BN / 16;
    __shared__ u16 AhT[2][BM][BK], AlT[2][BM][BK], BhT[2][BN][BK], BlT[2][BN][BK];
    const int tid = threadIdx.x, lane = tid & 63, wid = tid >> 6;
    const int wr = wid >> 1, wc = wid & 1;
    const int lr = lane & 15;
    const int sw = (lane >> 1) & 3;
    const int lkq = ((lane >> 4) ^ sw) * 8;              // swizzled read col-block
    const int bm0 = blockIdx.y * BM, bn0 = blockIdx.x * BN;
    const int srow = lane >> 2;
    const int scol_ = ((lane & 3) ^ ((lane >> 3) & 3)) * 8;   // pre-swizzled source col

    int kbeg = 0, kend = K;
    if (EPI == 5) {
        int ks = K / gridDim.z;
        kbeg = blockIdx.z * ks;
        kend = kbeg + ks;
    }
    const int nt = (kend - kbeg) / BK;

    auto STAGE = [&](int buf, int k0) {
        int ci = 0;
        #pragma unroll
        for (int c = 0; c < CH_A; c++, ci++) if ((ci & 3) == wid) {
            size_t g = (size_t)(bm0 + c * 16 + srow) * K + (k0 + scol_);
            async16(Ah + g, (u16*)&AhT[buf][0][0] + c * 512 + lane * 8);
        }
        #pragma unroll
        for (int c = 0; c < CH_A; c++, ci++) if ((ci & 3) == wid) {
            size_t g = (size_t)(bm0 + c * 16 + srow) * K + (k0 + scol_);
            async16(Al + g, (u16*)&AlT[buf][0][0] + c * 512 + lane * 8);
        }
        #pragma unroll
        for (int c = 0; c < CH_B; c++, ci++) if ((ci & 3) == wid) {
            size_t g = (size_t)(bn0 + c * 16 + srow) * K + (k0 + scol_);
            async16(Bh + g, (u16*)&BhT[buf][0][0] + c * 512 + lane * 8);
        }
        #pragma unroll
        for (int c = 0; c < CH_B; c++, ci++) if ((ci & 3) == wid) {
            size_t g = (size_t)(bn0 + c * 16 + srow) * K + (k0 + scol_);
            async16(Bl + g, (u16*)&BlT[buf][0][0] + c * 512 + lane * 8);
        }
    };

    f32x4 acc[MF][NF];
    #pragma unroll
    for (int i = 0; i < MF; i++)
        #pragma unroll
        for (int j = 0; j < NF; j++) acc[i][j] = (f32x4){0.f, 0.f, 0.f, 0.f};

    if constexpr (FAST) {
        // K <= 2*BK: stage both tiles once, single wait+barrier, no LDS rewrite
        STAGE(0, kbeg);
        if (nt > 1) STAGE(1, kbeg + BK);
        asm volatile("s_waitcnt vmcnt(0)" ::: "memory");
        __builtin_amdgcn_s_barrier();
        #pragma unroll
        for (int t = 0; t < 2; ++t) {
            if (t == 1 && nt < 2) break;
            short8 ah[MF], al[MF], bh[NF], bl[NF];
            #pragma unroll
            for (int i = 0; i < MF; i++) {
                int r = wr * (MF * 16) + i * 16 + lr;
                ah[i] = *(const short8*)&AhT[t][r][lkq];
                al[i] = *(const short8*)&AlT[t][r][lkq];
            }
            #pragma unroll
            for (int j = 0; j < NF; j++) {
                int r = wc * (NF * 16) + j * 16 + lr;
                bh[j] = *(const short8*)&BhT[t][r][lkq];
                bl[j] = *(const short8*)&BlT[t][r][lkq];
            }
            asm volatile("s_waitcnt lgkmcnt(0)" ::: "memory");
            __builtin_amdgcn_sched_barrier(0);
            #pragma unroll
            for (int i = 0; i < MF; i++)
                #pragma unroll
                for (int j = 0; j < NF; j++) {
                    acc[i][j] = __builtin_amdgcn_mfma_f32_16x16x32_bf16(ah[i], bh[j], acc[i][j], 0, 0, 0);
                    acc[i][j] = __builtin_amdgcn_mfma_f32_16x16x32_bf16(ah[i], bl[j], acc[i][j], 0, 0, 0);
                    acc[i][j] = __builtin_amdgcn_mfma_f32_16x16x32_bf16(al[i], bh[j], acc[i][j], 0, 0, 0);
                }
        }
    } else {
        // prologue: fill buffer 0
        STAGE(0, kbeg);
        asm volatile("s_waitcnt vmcnt(0)" ::: "memory");
        __builtin_amdgcn_s_barrier();

        for (int t = 0; t < nt; ++t) {
            const int cur = t & 1;
            // issue next tile's loads first — they fly under this tile's ds_read+MFMA
            if (t + 1 < nt) STAGE(cur ^ 1, kbeg + (t + 1) * BK);

            short8 ah[MF], al[MF], bh[NF], bl[NF];
            #pragma unroll
            for (int i = 0; i < MF; i++) {
                int r = wr * (MF * 16) + i * 16 + lr;
                ah[i] = *(const short8*)&AhT[cur][r][lkq];
                al[i] = *(const short8*)&AlT[cur][r][lkq];
            }
            #pragma unroll
            for (int j = 0; j < NF; j++) {
                int r = wc * (NF * 16) + j * 16 + lr;
                bh[j] = *(const short8*)&BhT[cur][r][lkq];
                bl[j] = *(const short8*)&BlT[cur][r][lkq];
            }
            asm volatile("s_waitcnt lgkmcnt(0)" ::: "memory");
            __builtin_amdgcn_sched_barrier(0);
            __builtin_amdgcn_s_setprio(1);
            #pragma unroll
            for (int i = 0; i < MF; i++)
                #pragma unroll
                for (int j = 0; j < NF; j++) {
                    acc[i][j] = __builtin_amdgcn_mfma_f32_16x16x32_bf16(ah[i], bh[j], acc[i][j], 0, 0, 0);
                    acc[i][j] = __builtin_amdgcn_mfma_f32_16x16x32_bf16(ah[i], bl[j], acc[i][j], 0, 0, 0);
                    acc[i][j] = __builtin_amdgcn_mfma_f32_16x16x32_bf16(al[i], bh[j], acc[i][j], 0, 0, 0);
                }
            __builtin_amdgcn_s_setprio(0);
            if (t + 1 < nt) {
                // next buffer staged (own loads landed) + all waves done reading cur
                asm volatile("s_waitcnt vmcnt(0)" ::: "memory");
                __builtin_amdgcn_s_barrier();
            }
        }
    }

    float* Cp = C;
    if (EPI == 5) Cp = C + (size_t)blockIdx.z * M * N;
    #pragma unroll
    for (int i = 0; i < MF; i++)
        #pragma unroll
        for (int j = 0; j < NF; j++) {
            int rowg = bm0 + wr * (MF * 16) + i * 16 + (lane >> 4) * 4;
            int colg = bn0 + wc * (NF * 16) + j * 16 + lr;
            #pragma unroll
            for (int q = 0; q < 4; q++) {
                float v = acc[i][j][q];
                if (EPI == 5) {
                    Cp[(size_t)(rowg + q) * N + colg] = v;
                } else if (EPI == 2) {
                    C[(size_t)(rowg + q) * N + colg] = softplusf_(v + aux[colg]);
                } else if (EPI == 4) {
                    if (colg < DI) {
                        size_t o = (size_t)(rowg + q) * DI + colg;
                        u16 hh = f2bf(v);
                        U1[o] = hh;
                        U2[o] = f2bf(v - bf2f(hh));
                    } else {
                        C2[(size_t)(rowg + q) * DI + (colg - DI)] = v * sigmoidf_(v);
                    }
                }
            }
        }
}

// ---------------- bcd split-K reduce ----------------
__global__ __launch_bounds__(256) void bcd_reduce_k(const float* __restrict__ partial,
                                                    float* __restrict__ bcd,
                                                    u16* __restrict__ bH,
                                                    u16* __restrict__ bL) {
    const int NT = Lseq * 96;
    int t = blockIdx.x * 256 + threadIdx.x;
    float s = 0.f;
    #pragma unroll
    for (int z = 0; z < SPLITK; z++) s += partial[(size_t)z * NT + t];
    bcd[t] = s;
    int col = t % 96, row = t / 96;
    if (col < DRr) {
        u16 h = f2bf(s);
        bH[(size_t)row * DRr + col] = h;
        bL[(size_t)row * DRr + col] = f2bf(s - bf2f(h));
    }
}

// ---------------- out split-K=4 reduce + residual ----------------
__global__ __launch_bounds__(256) void out_reduce_k(const float* __restrict__ part,
                                                    const float* __restrict__ x,
                                                    float* __restrict__ out) {
    int t = blockIdx.x * 256 + threadIdx.x;
    const size_t NT = (size_t)Lseq * Dmod;
    float4 xv = reinterpret_cast<const float4*>(x)[t];
    float4 o = xv;
    #pragma unroll
    for (int z = 0; z < OSPLIT; z++) {
        float4 p = reinterpret_cast<const float4*>(part + (size_t)z * NT)[t];
        o.x += p.x; o.y += p.y; o.z += p.z; o.w += p.w;
    }
    reinterpret_cast<float4*>(out)[t] = o;
}

// ---------------- Scan pass 1 ----------------
__global__ __launch_bounds__(256) void scan1_k(const float* __restrict__ delta,
                                               const u16* __restrict__ xcH,
                                               const u16* __restrict__ xcL,
                                               const float* __restrict__ bcd,
                                               const float* __restrict__ lmA,
                                               float* __restrict__ Pb,
                                               float* __restrict__ Sb) {
    __shared__ float Bs[LCHUNK][16];
    const int tid = threadIdx.x;
    const int d = (blockIdx.x * 256 + tid) >> 1;
    const int half = tid & 1;
    const int c = blockIdx.y;
    const int l0 = c * LCHUNK;
    {
        int row = tid >> 2, q = (tid & 3) * 4;
        float4 v = *reinterpret_cast<const float4*>(&bcd[(size_t)(l0 + row) * 96 + DRr + q]);
        *reinterpret_cast<float4*>(&Bs[row][q]) = v;
    }
    __syncthreads();
    float negA[8], h[8];
    #pragma unroll
    for (int j = 0; j < 8; j++) {
        negA[j] = -__expf(lmA[(size_t)d * Nst + half * 8 + j]);
        h[j] = 0.f;
    }
    float sdv = 0.f;
    for (int l = 0; l < LCHUNK; ++l) {
        size_t o = (size_t)(l0 + l) * DI + d;
        float dv = delta[o];
        float xcv = bf2f(xcH[o]) + bf2f(xcL[o]);
        sdv += dv;
        float dvx = dv * xcv;
        #pragma unroll
        for (int j = 0; j < 8; j++) {
            float a = __expf(dv * negA[j]);
            h[j] = fmaf(a, h[j], dvx * Bs[l][half * 8 + j]);
        }
    }
    size_t base = ((size_t)c * DI + d) * Nst + half * 8;
    #pragma unroll
    for (int j = 0; j < 8; j++) {
        Pb[base + j] = __expf(sdv * negA[j]);
        Sb[base + j] = h[j];
    }
}

// ---------------- Scan pass 2: combine in place (Pb -> Hinit) ----------------
__global__ __launch_bounds__(256) void scan2_k(float* __restrict__ PH,
                                               const float* __restrict__ Sb) {
    int t = blockIdx.x * 256 + threadIdx.x;
    float H = 0.f;
    for (int c = 0; c < NCHUNK; c++) {
        size_t idx = (size_t)c * (DI * Nst) + t;
        float P = PH[idx], S = Sb[idx];
        PH[idx] = H;
        H = S + P * H;
    }
}

// ---------------- Scan pass 3 ----------------
__global__ __launch_bounds__(256) void scan3_k(const float* __restrict__ delta,
                                               const u16* __restrict__ xcH,
                                               const u16* __restrict__ xcL,
                                               const float* __restrict__ bcd,
                                               const float* __restrict__ lmA,
                                               const float* __restrict__ Dp,
                                               const float* __restrict__ gate,
                                               const float* __restrict__ Hinit,
                                               u16* __restrict__ yH,
                                               u16* __restrict__ yL) {
    __shared__ float BCs[LCHUNK][32];
    const int tid = threadIdx.x;
    const int d = (blockIdx.x * 256 + tid) >> 1;
    const int half = tid & 1;
    const int c = blockIdx.y;
    const int l0 = c * LCHUNK;
    #pragma unroll
    for (int i = 0; i < 2; i++) {
        int idx = tid + 256 * i;
        int row = idx >> 3, q = (idx & 7) * 4;
        float4 v = *reinterpret_cast<const float4*>(&bcd[(size_t)(l0 + row) * 96 + DRr + q]);
        *reinterpret_cast<float4*>(&BCs[row][q]) = v;
    }
    __syncthreads();
    float negA[8], h[8];
    size_t hbase = ((size_t)c * DI + d) * Nst + half * 8;
    #pragma unroll
    for (int j = 0; j < 8; j++) {
        negA[j] = -__expf(lmA[(size_t)d * Nst + half * 8 + j]);
        h[j] = Hinit[hbase + j];
    }
    float Dpv = Dp[d];
    for (int l = 0; l < LCHUNK; ++l) {
        size_t o = (size_t)(l0 + l) * DI + d;
        float dv = delta[o];
        float xcv = bf2f(xcH[o]) + bf2f(xcL[o]);
        float dvx = dv * xcv;
        float yp = 0.f;
        #pragma unroll
        for (int j = 0; j < 8; j++) {
            float a = __expf(dv * negA[j]);
            h[j] = fmaf(a, h[j], dvx * BCs[l][half * 8 + j]);
            yp = fmaf(BCs[l][16 + half * 8 + j], h[j], yp);
        }
        yp += __shfl_xor(yp, 1);
        if (half == 0) {
            float yv = (yp + xcv * Dpv) * gate[o];
            u16 hq = f2bf(yv);
            yH[o] = hq;
            yL[o] = f2bf(yv - bf2f(hq));
        }
    }
}

extern "C" void kernel_launch(void* const* d_in, const int* in_sizes, int n_in,
                              void* d_out, int out_size, void* d_ws, size_t ws_size,
                              hipStream_t stream) {
    const float* x          = (const float*)d_in[0];
    const float* rms_w      = (const float*)d_in[1];
    const float* in_proj_w  = (const float*)d_in[2];
    const float* conv_w     = (const float*)d_in[3];
    const float* conv_b     = (const float*)d_in[4];
    const float* bcd_w      = (const float*)d_in[5];
    const float* dup_w      = (const float*)d_in[6];
    const float* dup_b      = (const float*)d_in[7];
    const float* lmA        = (const float*)d_in[8];
    const float* Dp         = (const float*)d_in[9];
    const float* out_proj_w = (const float*)d_in[10];
    float* out = (float*)d_out;
    char*  W   = (char*)d_ws;

    const size_t MB = 1ull << 20;
    // Region A: 0-16MB  : WiH/WiL -> delta
    u16*   WiH  = (u16*)(W + 0);
    u16*   WiL  = (u16*)(W + 8 * MB);
    float* delta= (float*)(W + 0);
    // Region B: 16-32MB : xsH/xsL -> part(12) -> Sb(4) -> yH/yL(16)
    u16*   xsH  = (u16*)(W + 16 * MB);
    u16*   xsL  = (u16*)(W + 24 * MB);
    float* part = (float*)(W + 16 * MB);
    float* Sb   = (float*)(W + 16 * MB);
    u16*   yH   = (u16*)(W + 16 * MB);
    u16*   yL   = (u16*)(W + 24 * MB);
    // Region C+D: 32-64MB : gate(16) + xcH/xcL(16) -> opart (32MB, post-scan3)
    float* gate = (float*)(W + 32 * MB);
    u16*   xcH  = (u16*)(W + 48 * MB);
    u16*   xcL  = (u16*)(W + 56 * MB);
    float* opart= (float*)(W + 32 * MB);
    // Region E: 64-72MB : xnH/xnL -> WoH/WoL
    u16*   xnH  = (u16*)(W + 64 * MB);
    u16*   xnL  = (u16*)(W + 68 * MB);
    u16*   WoH  = (u16*)(W + 64 * MB);
    u16*   WoL  = (u16*)(W + 68 * MB);
    // Region F: 72-77MB : bcd f32 (72MB) + small weights (73-74.75MB, written step 3,
    //                     read steps 4-5, dead before Pb) + Pb (73-77MB, scan1+)
    float* bcd  = (float*)(W + 72 * MB);
    u16*   bwTH = (u16*)(W + 73 * MB);
    u16*   bwTL = (u16*)(W + 73 * MB + 384 * 1024);
    u16*   dwTH = (u16*)(W + 73 * MB + 768 * 1024);
    u16*   dwTL = (u16*)(W + 73 * MB + 1024 * 1024);
    u16*   bcdH = (u16*)(W + 73 * MB + 1280 * 1024);
    u16*   bcdL = (u16*)(W + 73 * MB + 1536 * 1024);
    float* Pb   = (float*)(W + 73 * MB);

    // 1. fused: RMSNorm + in_proj_w transpose/split
    prep1_k<<<2048 + 4096, 256, 0, stream>>>(x, rms_w, xnH, xnL, in_proj_w, WiH, WiL);
    // 2. in_proj: xs (split bf16) / gate  (128x128, R11 pipeline)
    gemm_mfma3<128, 128, 4><<<dim3(4096 / 128, Lseq / 128), 256, 0, stream>>>(
        xnH, xnL, WiH, WiL, nullptr, gate, xsH, xsL, nullptr, Lseq, 2 * DI, Dmod);
    // 3. fused mid: conv+silu (512 blk) + out_proj/bcd/dup weight prep (2368 blk)
    mid_k<<<512 + 2368, 256, 0, stream>>>(xsH, xsL, conv_w, conv_b, xcH, xcL,
                                          out_proj_w, bcd_w, dup_w,
                                          WoH, WoL, bwTH, bwTL, dwTH, dwTL);
    // 4. bcd = xc @ bcd_w (split-K MFMA + reduce)
    gemm_mfma3<128, 96, 5><<<dim3(1, Lseq / 128, SPLITK), 256, 0, stream>>>(
        xcH, xcL, bwTH, bwTL, part, nullptr, nullptr, nullptr, nullptr, Lseq, 96, DI);
    bcd_reduce_k<<<Lseq * 96 / 256, 256, 0, stream>>>(part, bcd, bcdH, bcdL);
    // 5. delta = softplus(bcd[:, :64] @ dup_w + dup_b)  (compile-time FAST: nt==2)
    gemm_mfma3<64, 128, 2, true><<<dim3(DI / 128, Lseq / 64), 256, 0, stream>>>(
        bcdH, bcdL, dwTH, dwTL, delta, nullptr, nullptr, nullptr, dup_b, Lseq, DI, DRr);
    // 6-8. chunked selective scan (scan1 overwrites the small-weight region with Pb)
    scan1_k<<<dim3(16, NCHUNK), 256, 0, stream>>>(delta, xcH, xcL, bcd, lmA, Pb, Sb);
    scan2_k<<<dim3(DI * Nst / 256), 256, 0, stream>>>(Pb, Sb);
    scan3_k<<<dim3(16, NCHUNK), 256, 0, stream>>>(delta, xcH, xcL, bcd, lmA, Dp, gate, Pb, yH, yL);
    // 9. out_proj: 128x128 + split-K=4, reduce + residual
    gemm_mfma3<128, 128, 5><<<dim3(Dmod / 128, Lseq / 128, OSPLIT), 256, 0, stream>>>(
        yH, yL, WoH, WoL, opart, nullptr, nullptr, nullptr, nullptr, Lseq, Dmod, DI);
    out_reduce_k<<<Lseq * Dmod / 1024, 256, 0, stream>>>(opart, x, out);
}